// Round 11
// baseline (134.839 us; speedup 1.0000x reference)
//
#include <hip/hip_runtime.h>

constexpr int M_ROWS = 16000;   // B*T
constexpr int DIM    = 512;
constexpr int NEXP   = 10;
constexpr int NSH    = 5;
constexpr int KTOP   = 5;

constexpr int TMA = 64;         // rows per gemm block
constexpr int NCB = 256;        // cols per gemm block (2 col-blocks)
constexpr int BK  = 32;         // k-tile
constexpr int NT  = DIM / BK;   // 16

constexpr int TMF = 32;         // rows per finalize block

typedef __attribute__((ext_vector_type(8))) short  bf16x8;
typedef __attribute__((ext_vector_type(4))) float  f32x4;

#define SB __builtin_amdgcn_sched_barrier(0)

__device__ inline unsigned short bf16_rne(float x) {
    unsigned u = __float_as_uint(x);
    u += 0x7fffu + ((u >> 16) & 1u);
    return (unsigned short)(u >> 16);
}
__device__ inline float bf16_to_f(unsigned short h) {
    return __uint_as_float(((unsigned)h) << 16);
}

// ---------------- prep: W1 -> (hi,lo) bf16 [N][K]; shsum = sum_s shared_w ----
__global__ __launch_bounds__(256)
void prep_kernel(const float* __restrict__ W1, const float* __restrict__ shared_w,
                 unsigned short* __restrict__ w1hi, unsigned short* __restrict__ w1lo,
                 float* __restrict__ shsum)
{
    int b = blockIdx.x;
    if (b < 256) {
        int f = b * 256 + threadIdx.x;
        float4 v = *reinterpret_cast<const float4*>(&W1[(size_t)f * 4]);
        float xs[4] = {v.x, v.y, v.z, v.w};
        ushort4 h4, l4;
        unsigned short h[4], l[4];
        #pragma unroll
        for (int i = 0; i < 4; ++i) {
            h[i] = bf16_rne(xs[i]);
            float rem = xs[i] - bf16_to_f(h[i]);
            l[i] = bf16_rne(rem);
        }
        h4.x = h[0]; h4.y = h[1]; h4.z = h[2]; h4.w = h[3];
        l4.x = l[0]; l4.y = l[1]; l4.z = l[2]; l4.w = l[3];
        *reinterpret_cast<ushort4*>(&w1hi[(size_t)f * 4]) = h4;
        *reinterpret_cast<ushort4*>(&w1lo[(size_t)f * 4]) = l4;
    } else {
        for (int c = threadIdx.x; c < DIM; c += 256) {
            float s = 0.f;
            #pragma unroll
            for (int e = 0; e < NSH; ++e) s += shared_w[e * DIM + c];
            shsum[c] = s;
        }
    }
}

// ================= PROBE KERNELS (diagnostic; write to scratch only) ========
// All mirror R7's gemm geometry exactly: 500 blocks x 512 thr, 80 KB LDS.

// ---- probe A: staging only (B gload_lds + A load/convert/ds_write) + bar ----
__global__ __launch_bounds__(512, 4)
void pA_stageAB(const float* __restrict__ G,
                const unsigned short* __restrict__ w1hi,
                const unsigned short* __restrict__ w1lo,
                float* __restrict__ probe_out)
{
    __shared__ unsigned short smem[40960];
    const int tid = threadIdx.x;
    const int bx = blockIdx.x;
    const int colblk = bx & 1;
    const int row0 = (bx >> 1) * TMA;
    const int cb = colblk * NCB;
    const int arow = tid >> 3, aq = tid & 7;
    const int acol = ((aq >> 1) ^ ((arow >> 1) & 3)) * 8 + (aq & 1) * 4;

    auto stageB = [&](int t, int buf) {
        unsigned short* bh = smem + buf * 20480;
        unsigned short* bl = bh + 8192;
        #pragma unroll
        for (int r = 0; r < 2; ++r) {
            int f = r * 512 + tid;
            int n = f >> 2;
            int js = (f & 3) ^ ((n >> 1) & 3);
            __builtin_amdgcn_global_load_lds(
                (const __attribute__((address_space(1))) void*)(w1hi + (size_t)(cb + n) * DIM + t * BK + js * 8),
                (__attribute__((address_space(3))) void*)(bh + f * 8), 16, 0, 0);
        }
        #pragma unroll
        for (int r = 0; r < 2; ++r) {
            int f = r * 512 + tid;
            int n = f >> 2;
            int js = (f & 3) ^ ((n >> 1) & 3);
            __builtin_amdgcn_global_load_lds(
                (const __attribute__((address_space(1))) void*)(w1lo + (size_t)(cb + n) * DIM + t * BK + js * 8),
                (__attribute__((address_space(3))) void*)(bl + f * 8), 16, 0, 0);
        }
    };
    auto stageA = [&](int t, int buf) {
        float4 g4 = *reinterpret_cast<const float4*>(
                        &G[(size_t)(row0 + arow) * DIM + t * BK + aq * 4]);
        float xs[4] = {g4.x, g4.y, g4.z, g4.w};
        unsigned short h[4], l[4];
        #pragma unroll
        for (int i = 0; i < 4; ++i) {
            h[i] = bf16_rne(xs[i]);
            l[i] = bf16_rne(xs[i] - bf16_to_f(h[i]));
        }
        ushort4 h4, l4;
        h4.x = h[0]; h4.y = h[1]; h4.z = h[2]; h4.w = h[3];
        l4.x = l[0]; l4.y = l[1]; l4.z = l[2]; l4.w = l[3];
        unsigned short* ab = smem + buf * 20480 + 16384;
        *reinterpret_cast<ushort4*>(&ab[arow * 32 + acol])        = h4;
        *reinterpret_cast<ushort4*>(&ab[2048 + arow * 32 + acol]) = l4;
    };

    stageB(0, 0); stageA(0, 0);
    __syncthreads();
    for (int t = 0; t < NT - 1; ++t) {
        stageB(t + 1, (t & 1) ^ 1);
        stageA(t + 1, (t & 1) ^ 1);
        __syncthreads();
    }
    float s = (float)smem[tid] + (float)smem[20480 + tid];   // keep-alive
    probe_out[(size_t)bx * 512 + tid] = s;
}

// ---- probe B: B-staging only + barriers ----
__global__ __launch_bounds__(512, 4)
void pB_stageBonly(const unsigned short* __restrict__ w1hi,
                   const unsigned short* __restrict__ w1lo,
                   float* __restrict__ probe_out)
{
    __shared__ unsigned short smem[40960];
    const int tid = threadIdx.x;
    const int bx = blockIdx.x;
    const int cb = (bx & 1) * NCB;

    auto stageB = [&](int t, int buf) {
        unsigned short* bh = smem + buf * 20480;
        unsigned short* bl = bh + 8192;
        #pragma unroll
        for (int r = 0; r < 2; ++r) {
            int f = r * 512 + tid;
            int n = f >> 2;
            int js = (f & 3) ^ ((n >> 1) & 3);
            __builtin_amdgcn_global_load_lds(
                (const __attribute__((address_space(1))) void*)(w1hi + (size_t)(cb + n) * DIM + t * BK + js * 8),
                (__attribute__((address_space(3))) void*)(bh + f * 8), 16, 0, 0);
        }
        #pragma unroll
        for (int r = 0; r < 2; ++r) {
            int f = r * 512 + tid;
            int n = f >> 2;
            int js = (f & 3) ^ ((n >> 1) & 3);
            __builtin_amdgcn_global_load_lds(
                (const __attribute__((address_space(1))) void*)(w1lo + (size_t)(cb + n) * DIM + t * BK + js * 8),
                (__attribute__((address_space(3))) void*)(bl + f * 8), 16, 0, 0);
        }
    };

    stageB(0, 0);
    __syncthreads();
    for (int t = 0; t < NT - 1; ++t) {
        stageB(t + 1, (t & 1) ^ 1);
        __syncthreads();
    }
    float s = (float)smem[tid] + (float)smem[20480 + tid];
    probe_out[(size_t)bx * 512 + tid] = s;
}

// ---- shared compute-probe body: stage both bufs once, then 16x {frag+MFMA} --
template <bool USE_BARRIER>
__device__ __forceinline__ void comp_probe_body(
    const float* __restrict__ G,
    const unsigned short* __restrict__ w1hi,
    const unsigned short* __restrict__ w1lo,
    float* __restrict__ probe_out)
{
    __shared__ unsigned short smem[40960];
    const int tid  = threadIdx.x;
    const int lane = tid & 63;
    const int wv   = tid >> 6;
    const int l15  = lane & 15;
    const int lg   = lane >> 4;
    const int rgrp = wv >> 2;
    const int cgrp = wv & 3;
    const int bx = blockIdx.x;
    const int colblk = bx & 1;
    const int row0 = (bx >> 1) * TMA;
    const int cb = colblk * NCB;
    const int arow = tid >> 3, aq = tid & 7;
    const int acol = ((aq >> 1) ^ ((arow >> 1) & 3)) * 8 + (aq & 1) * 4;

    auto stageB = [&](int t, int buf) {
        unsigned short* bh = smem + buf * 20480;
        unsigned short* bl = bh + 8192;
        #pragma unroll
        for (int r = 0; r < 2; ++r) {
            int f = r * 512 + tid;
            int n = f >> 2;
            int js = (f & 3) ^ ((n >> 1) & 3);
            __builtin_amdgcn_global_load_lds(
                (const __attribute__((address_space(1))) void*)(w1hi + (size_t)(cb + n) * DIM + t * BK + js * 8),
                (__attribute__((address_space(3))) void*)(bh + f * 8), 16, 0, 0);
        }
        #pragma unroll
        for (int r = 0; r < 2; ++r) {
            int f = r * 512 + tid;
            int n = f >> 2;
            int js = (f & 3) ^ ((n >> 1) & 3);
            __builtin_amdgcn_global_load_lds(
                (const __attribute__((address_space(1))) void*)(w1lo + (size_t)(cb + n) * DIM + t * BK + js * 8),
                (__attribute__((address_space(3))) void*)(bl + f * 8), 16, 0, 0);
        }
    };
    auto stageA = [&](int t, int buf) {
        float4 g4 = *reinterpret_cast<const float4*>(
                        &G[(size_t)(row0 + arow) * DIM + t * BK + aq * 4]);
        float xs[4] = {g4.x, g4.y, g4.z, g4.w};
        unsigned short h[4], l[4];
        #pragma unroll
        for (int i = 0; i < 4; ++i) {
            h[i] = bf16_rne(xs[i]);
            l[i] = bf16_rne(xs[i] - bf16_to_f(h[i]));
        }
        ushort4 h4, l4;
        h4.x = h[0]; h4.y = h[1]; h4.z = h[2]; h4.w = h[3];
        l4.x = l[0]; l4.y = l[1]; l4.z = l[2]; l4.w = l[3];
        unsigned short* ab = smem + buf * 20480 + 16384;
        *reinterpret_cast<ushort4*>(&ab[arow * 32 + acol])        = h4;
        *reinterpret_cast<ushort4*>(&ab[2048 + arow * 32 + acol]) = l4;
    };

    stageB(0, 0); stageA(0, 0);
    stageB(1, 1); stageA(1, 1);
    __syncthreads();

    f32x4 acc[2][4];
    #pragma unroll
    for (int rt = 0; rt < 2; ++rt)
        #pragma unroll
        for (int ct = 0; ct < 4; ++ct) acc[rt][ct] = (f32x4)0.f;

    for (int t = 0; t < NT; ++t) {
        asm volatile("" ::: "memory");      // block ds_read hoisting (rule #17)
        const int cur = t & 1;
        unsigned short* base = smem + cur * 20480;
        bf16x8 ah[2], al[2], bh[4], bl[4];
        #pragma unroll
        for (int rt = 0; rt < 2; ++rt) {
            int r_ = rgrp * 32 + rt * 16 + l15;
            int cs = (lg ^ ((r_ >> 1) & 3)) * 8;
            ah[rt] = *reinterpret_cast<const bf16x8*>(&base[16384 + r_ * 32 + cs]);
            al[rt] = *reinterpret_cast<const bf16x8*>(&base[18432 + r_ * 32 + cs]);
        }
        #pragma unroll
        for (int ct = 0; ct < 4; ++ct) {
            int n  = cgrp * 64 + ct * 16 + l15;
            int cs = (lg ^ ((n >> 1) & 3)) * 8;
            bh[ct] = *reinterpret_cast<const bf16x8*>(&base[n * 32 + cs]);
            bl[ct] = *reinterpret_cast<const bf16x8*>(&base[8192 + n * 32 + cs]);
        }
        #pragma unroll
        for (int ct = 0; ct < 4; ++ct)
            #pragma unroll
            for (int rt = 0; rt < 2; ++rt)
                acc[rt][ct] = __builtin_amdgcn_mfma_f32_16x16x32_bf16(ah[rt], bh[ct], acc[rt][ct], 0, 0, 0);
        #pragma unroll
        for (int ct = 0; ct < 4; ++ct)
            #pragma unroll
            for (int rt = 0; rt < 2; ++rt)
                acc[rt][ct] = __builtin_amdgcn_mfma_f32_16x16x32_bf16(al[rt], bh[ct], acc[rt][ct], 0, 0, 0);
        #pragma unroll
        for (int ct = 0; ct < 4; ++ct)
            #pragma unroll
            for (int rt = 0; rt < 2; ++rt)
                acc[rt][ct] = __builtin_amdgcn_mfma_f32_16x16x32_bf16(ah[rt], bl[ct], acc[rt][ct], 0, 0, 0);
        if (USE_BARRIER) __syncthreads(); else SB;
    }

    float s = 0.f;
    #pragma unroll
    for (int rt = 0; rt < 2; ++rt)
        #pragma unroll
        for (int ct = 0; ct < 4; ++ct)
            #pragma unroll
            for (int j = 0; j < 4; ++j) s += acc[rt][ct][j];
    probe_out[(size_t)bx * 512 + tid] = s;     // keep acc alive
}

__global__ __launch_bounds__(512, 4)
void pD_compbar(const float* __restrict__ G,
                const unsigned short* __restrict__ w1hi,
                const unsigned short* __restrict__ w1lo,
                float* __restrict__ probe_out)
{ comp_probe_body<true>(G, w1hi, w1lo, probe_out); }

__global__ __launch_bounds__(512, 4)
void pE_compnobar(const float* __restrict__ G,
                  const unsigned short* __restrict__ w1hi,
                  const unsigned short* __restrict__ w1lo,
                  float* __restrict__ probe_out)
{ comp_probe_body<false>(G, w1hi, w1lo, probe_out); }

// ================= REAL KERNELS (round-7 verbatim, verified) ================
__global__ __launch_bounds__(512, 4)
void gemm_logits(const float* __restrict__ G,
                 const unsigned short* __restrict__ w1hi,
                 const unsigned short* __restrict__ w1lo,
                 const float* __restrict__ W2,
                 float* __restrict__ plogG)
{
    __shared__ unsigned short smem[40960];   // 81920 B

    const int tid  = threadIdx.x;
    const int lane = tid & 63;
    const int wv   = tid >> 6;          // 0..7
    const int l15  = lane & 15;
    const int lg   = lane >> 4;
    const int rgrp = wv >> 2;           // 0..1
    const int cgrp = wv & 3;            // 0..3
    const int bx     = blockIdx.x;
    const int colblk = bx & 1;
    const int row0   = (bx >> 1) * TMA;
    const int cb     = colblk * NCB;

    const int arow = tid >> 3;          // 0..63
    const int aq   = tid & 7;
    const int acol = ((aq >> 1) ^ ((arow >> 1) & 3)) * 8 + (aq & 1) * 4;

    f32x4 acc[2][4];
    #pragma unroll
    for (int rt = 0; rt < 2; ++rt)
        #pragma unroll
        for (int ct = 0; ct < 4; ++ct) acc[rt][ct] = (f32x4)0.f;

    auto stageB = [&](int t, int buf) {
        unsigned short* bh = smem + buf * 20480;
        unsigned short* bl = bh + 8192;
        #pragma unroll
        for (int r = 0; r < 2; ++r) {
            int f = r * 512 + tid;
            int n = f >> 2;
            int j = f & 3;
            int js = j ^ ((n >> 1) & 3);
            __builtin_amdgcn_global_load_lds(
                (const __attribute__((address_space(1))) void*)(w1hi + (size_t)(cb + n) * DIM + t * BK + js * 8),
                (__attribute__((address_space(3))) void*)(bh + f * 8), 16, 0, 0);
        }
        #pragma unroll
        for (int r = 0; r < 2; ++r) {
            int f = r * 512 + tid;
            int n = f >> 2;
            int j = f & 3;
            int js = j ^ ((n >> 1) & 3);
            __builtin_amdgcn_global_load_lds(
                (const __attribute__((address_space(1))) void*)(w1lo + (size_t)(cb + n) * DIM + t * BK + js * 8),
                (__attribute__((address_space(3))) void*)(bl + f * 8), 16, 0, 0);
        }
    };
    auto stageA = [&](int t, int buf) {
        float4 g4 = *reinterpret_cast<const float4*>(
                        &G[(size_t)(row0 + arow) * DIM + t * BK + aq * 4]);
        float xs[4] = {g4.x, g4.y, g4.z, g4.w};
        unsigned short h[4], l[4];
        #pragma unroll
        for (int i = 0; i < 4; ++i) {
            h[i] = bf16_rne(xs[i]);
            float rem = xs[i] - bf16_to_f(h[i]);
            l[i] = bf16_rne(rem);
        }
        ushort4 h4, l4;
        h4.x = h[0]; h4.y = h[1]; h4.z = h[2]; h4.w = h[3];
        l4.x = l[0]; l4.y = l[1]; l4.z = l[2]; l4.w = l[3];
        unsigned short* ab = smem + buf * 20480 + 16384;
        *reinterpret_cast<ushort4*>(&ab[arow * 32 + acol])        = h4;
        *reinterpret_cast<ushort4*>(&ab[2048 + arow * 32 + acol]) = l4;
    };

    stageB(0, 0);
    stageA(0, 0);
    __syncthreads();

    for (int t = 0; t < NT; ++t) {
        const int cur = t & 1;
        if (t + 1 < NT) {
            stageB(t + 1, cur ^ 1);
            stageA(t + 1, cur ^ 1);
        }
        unsigned short* base = smem + cur * 20480;

        bf16x8 ah[2], al[2], bh[4], bl[4];
        #pragma unroll
        for (int rt = 0; rt < 2; ++rt) {
            int r_ = rgrp * 32 + rt * 16 + l15;
            int cs = (lg ^ ((r_ >> 1) & 3)) * 8;
            ah[rt] = *reinterpret_cast<const bf16x8*>(&base[16384 + r_ * 32 + cs]);
            al[rt] = *reinterpret_cast<const bf16x8*>(&base[18432 + r_ * 32 + cs]);
        }
        #pragma unroll
        for (int ct = 0; ct < 4; ++ct) {
            int n  = cgrp * 64 + ct * 16 + l15;
            int cs = (lg ^ ((n >> 1) & 3)) * 8;
            bh[ct] = *reinterpret_cast<const bf16x8*>(&base[n * 32 + cs]);
            bl[ct] = *reinterpret_cast<const bf16x8*>(&base[8192 + n * 32 + cs]);
        }
        #pragma unroll
        for (int ct = 0; ct < 4; ++ct)
            #pragma unroll
            for (int rt = 0; rt < 2; ++rt)
                acc[rt][ct] = __builtin_amdgcn_mfma_f32_16x16x32_bf16(ah[rt], bh[ct], acc[rt][ct], 0, 0, 0);
        #pragma unroll
        for (int ct = 0; ct < 4; ++ct)
            #pragma unroll
            for (int rt = 0; rt < 2; ++rt)
                acc[rt][ct] = __builtin_amdgcn_mfma_f32_16x16x32_bf16(al[rt], bh[ct], acc[rt][ct], 0, 0, 0);
        #pragma unroll
        for (int ct = 0; ct < 4; ++ct)
            #pragma unroll
            for (int rt = 0; rt < 2; ++rt)
                acc[rt][ct] = __builtin_amdgcn_mfma_f32_16x16x32_bf16(ah[rt], bl[ct], acc[rt][ct], 0, 0, 0);
        __syncthreads();
    }

    #pragma unroll
    for (int rt = 0; rt < 2; ++rt)
        #pragma unroll
        for (int ct = 0; ct < 4; ++ct)
            #pragma unroll
            for (int j = 0; j < 4; ++j)
                acc[rt][ct][j] = fmaxf(acc[rt][ct][j], 0.f);

    const int w8 = colblk * 4 + cgrp;
    #pragma unroll
    for (int e = 0; e < NEXP; ++e) {
        float w2v[4];
        #pragma unroll
        for (int ct = 0; ct < 4; ++ct)
            w2v[ct] = W2[(size_t)e * DIM + cb + cgrp * 64 + ct * 16 + l15];
        #pragma unroll
        for (int rt = 0; rt < 2; ++rt) {
            #pragma unroll
            for (int j = 0; j < 4; ++j) {
                float s = 0.f;
                #pragma unroll
                for (int ct = 0; ct < 4; ++ct)
                    s = fmaf(acc[rt][ct][j], w2v[ct], s);
                s += __shfl_xor(s, 1, 16);
                s += __shfl_xor(s, 2, 16);
                s += __shfl_xor(s, 4, 16);
                s += __shfl_xor(s, 8, 16);
                if (l15 == 0) {
                    int grow = row0 + rgrp * 32 + rt * 16 + lg * 4 + j;
                    plogG[((size_t)grow * 8 + w8) * NEXP + e] = s;
                }
            }
        }
    }
}

__global__ __launch_bounds__(256)
void finalize(const float* __restrict__ plogG, const float* __restrict__ value,
              const float* __restrict__ shsum, const float* __restrict__ routing_w,
              float* __restrict__ out)
{
    __shared__ float swls[TMF * NEXP];
    const int tid  = threadIdx.x;
    const int row0 = blockIdx.x * TMF;

    if (tid < TMF) {
        const float* pr = &plogG[(size_t)(row0 + tid) * 8 * NEXP];
        float lgt[NEXP];
        #pragma unroll
        for (int e = 0; e < NEXP; ++e) lgt[e] = 0.f;
        #pragma unroll
        for (int w = 0; w < 8; ++w)
            #pragma unroll
            for (int e = 0; e < NEXP; ++e)
                lgt[e] += pr[w * NEXP + e];

        float mx = lgt[0];
        #pragma unroll
        for (int e = 1; e < NEXP; ++e) mx = fmaxf(mx, lgt[e]);
        float p[NEXP], se = 0.f;
        #pragma unroll
        for (int e = 0; e < NEXP; ++e) { p[e] = expf(lgt[e] - mx); se += p[e]; }
        float inv = 1.f / se;
        #pragma unroll
        for (int e = 0; e < NEXP; ++e) p[e] *= inv;
        unsigned used = 0;
        #pragma unroll
        for (int t = 0; t < KTOP; ++t) {
            float bv = -1.f; int bi = 0;
            #pragma unroll
            for (int e = 0; e < NEXP; ++e) {
                bool better = (((used >> e) & 1u) == 0u) && (p[e] > bv);
                bv = better ? p[e] : bv;
                bi = better ? e : bi;
            }
            used |= 1u << bi;
        }
        #pragma unroll
        for (int e = 0; e < NEXP; ++e)
            swls[tid * NEXP + e] = ((used >> e) & 1u) ? p[e] : 0.f;
    }
    __syncthreads();

    const int c4 = (tid & 127) * 4;
    const int rh = tid >> 7;
    float4 sh4 = *reinterpret_cast<const float4*>(&shsum[c4]);
    float4 rw4[NEXP];
    #pragma unroll
    for (int e = 0; e < NEXP; ++e)
        rw4[e] = *reinterpret_cast<const float4*>(&routing_w[(size_t)e * DIM + c4]);
    #pragma unroll
    for (int r = 0; r < 16; ++r) {
        int row = rh * 16 + r;
        float val = value[row0 + row];
        float4 o = sh4;
        #pragma unroll
        for (int e = 0; e < NEXP; ++e) {
            float wgt = swls[row * NEXP + e];
            o.x = fmaf(wgt, rw4[e].x, o.x);
            o.y = fmaf(wgt, rw4[e].y, o.y);
            o.z = fmaf(wgt, rw4[e].z, o.z);
            o.w = fmaf(wgt, rw4[e].w, o.w);
        }
        o.x *= val; o.y *= val; o.z *= val; o.w *= val;
        *reinterpret_cast<float4*>(&out[(size_t)(row0 + row) * DIM + c4]) = o;
    }
}

extern "C" void kernel_launch(void* const* d_in, const int* in_sizes, int n_in,
                              void* d_out, int out_size, void* d_ws, size_t ws_size,
                              hipStream_t stream) {
    const float* G         = (const float*)d_in[0];
    const float* value     = (const float*)d_in[1];
    const float* shared_w  = (const float*)d_in[2];
    const float* routing_w = (const float*)d_in[3];
    const float* W1        = (const float*)d_in[4];
    const float* W2        = (const float*)d_in[5];
    float* out             = (float*)d_out;

    unsigned short* w1hi = (unsigned short*)d_ws;                        // 512 KB
    unsigned short* w1lo = (unsigned short*)((char*)d_ws + 524288);      // 512 KB
    float*          shs  = (float*)((char*)d_ws + 1048576);              // 2 KB
    float*          plg  = (float*)((char*)d_ws + 1056768);              // 5.12 MB

    prep_kernel<<<257, 256, 0, stream>>>(W1, shared_w, w1hi, w1lo, shs);

    // ---- diagnostic probes (write into plg scratch; real gemm overwrites) --
    pA_stageAB  <<<(M_ROWS / TMA) * 2, 512, 0, stream>>>(G, w1hi, w1lo, plg);
    pB_stageBonly<<<(M_ROWS / TMA) * 2, 512, 0, stream>>>(w1hi, w1lo, plg);
    pD_compbar  <<<(M_ROWS / TMA) * 2, 512, 0, stream>>>(G, w1hi, w1lo, plg);
    pE_compnobar<<<(M_ROWS / TMA) * 2, 512, 0, stream>>>(G, w1hi, w1lo, plg);

    // ---- real computation (round-7 verbatim) ----
    gemm_logits<<<(M_ROWS / TMA) * 2, 512, 0, stream>>>(G, w1hi, w1lo, W2, plg);
    finalize<<<M_ROWS / TMF, 256, 0, stream>>>(plg, value, shs, routing_w, out);
}

// Round 13
// 76.860 us; speedup vs baseline: 1.7543x; 1.7543x over previous
//
#include <hip/hip_runtime.h>

constexpr int M_ROWS = 16000;   // B*T
constexpr int DIM    = 512;
constexpr int NEXP   = 10;
constexpr int NSH    = 5;
constexpr int KTOP   = 5;

constexpr int TMA = 64;         // rows per gemm block
constexpr int NCB = 256;        // cols per gemm block (2 col-blocks)
constexpr int BK  = 32;         // k-tile
constexpr int NT  = DIM / BK;   // 16

constexpr int TMF = 32;         // rows per finalize block

typedef __attribute__((ext_vector_type(8))) short  bf16x8;
typedef __attribute__((ext_vector_type(4))) float  f32x4;

__device__ inline unsigned short bf16_rne(float x) {
    unsigned u = __float_as_uint(x);
    u += 0x7fffu + ((u >> 16) & 1u);
    return (unsigned short)(u >> 16);
}
__device__ inline float bf16_to_f(unsigned short h) {
    return __uint_as_float(((unsigned)h) << 16);
}

// ---------------- prep: W1 -> (hi,lo) bf16 [N][K]; shsum = sum_s shared_w ----
__global__ __launch_bounds__(256)
void prep_kernel(const float* __restrict__ W1, const float* __restrict__ shared_w,
                 unsigned short* __restrict__ w1hi, unsigned short* __restrict__ w1lo,
                 float* __restrict__ shsum)
{
    int b = blockIdx.x;
    if (b < 256) {
        int f = b * 256 + threadIdx.x;
        float4 v = *reinterpret_cast<const float4*>(&W1[(size_t)f * 4]);
        float xs[4] = {v.x, v.y, v.z, v.w};
        ushort4 h4, l4;
        unsigned short h[4], l[4];
        #pragma unroll
        for (int i = 0; i < 4; ++i) {
            h[i] = bf16_rne(xs[i]);
            float rem = xs[i] - bf16_to_f(h[i]);
            l[i] = bf16_rne(rem);
        }
        h4.x = h[0]; h4.y = h[1]; h4.z = h[2]; h4.w = h[3];
        l4.x = l[0]; l4.y = l[1]; l4.z = l[2]; l4.w = l[3];
        *reinterpret_cast<ushort4*>(&w1hi[(size_t)f * 4]) = h4;
        *reinterpret_cast<ushort4*>(&w1lo[(size_t)f * 4]) = l4;
    } else {
        for (int c = threadIdx.x; c < DIM; c += 256) {
            float s = 0.f;
            #pragma unroll
            for (int e = 0; e < NSH; ++e) s += shared_w[e * DIM + c];
            shsum[c] = s;
        }
    }
}

// ---------------- kernel A: 3-pass GEMM + partial logits ----------------
// Geometry == round 7 (verified: 45.7us, absmax 9.77e-4) with ONE change:
// Bl no longer staged in LDS — pass 3 reads Blo fragments global->reg
// (4 x dwordx4 per wave per tile, L2-resident w1lo, issued at top of iter,
// consumed after passes 1-2: ~300cyc self-hiding). LDS 80KB -> 48KB
// => 3 blocks/CU = 24 waves/CU (inter-block stagger: R11's ablation showed
// staging+compute ADD within a block; co-resident blocks overlap them).
// 250x2 blocks, 512 thr = 8 waves, wave (rgrp=wv>>2, cgrp=wv&3) = 32r x 64c,
// acc[2][4]. Per buf (shorts): Bh[256][32] @ 0, Ah[64][32] @ 8192, Al @ 10240;
// buf stride 12288. Chunk swizzle phys16B = logical^((row>>1)&3), pre-swizzled
// gload_lds SOURCE + swizzled reads (both-sides rule).
// BIT-EXACT (3-pass mandatory — R12 showed top-k flips are discontinuous,
// ~0.025 output impact each; 3-pass logit err ~1.5e-6 => zero flips, 7x
// verified): same bf16 values, per-acc pass order (hh,lh,hl), t ascending,
// same 64-col fmaf chain + width-16 butterfly, w8=colblk*4+cgrp, finalize
// sums w=0..7 sequentially.
__global__ __launch_bounds__(512, 6)
void gemm_logits(const float* __restrict__ G,
                 const unsigned short* __restrict__ w1hi,
                 const unsigned short* __restrict__ w1lo,
                 const float* __restrict__ W2,
                 float* __restrict__ plogG)
{
    __shared__ unsigned short smem[24576];   // 49152 B

    const int tid  = threadIdx.x;
    const int lane = tid & 63;
    const int wv   = tid >> 6;          // 0..7
    const int l15  = lane & 15;
    const int lg   = lane >> 4;
    const int rgrp = wv >> 2;           // 0..1
    const int cgrp = wv & 3;            // 0..3
    const int bx     = blockIdx.x;
    const int colblk = bx & 1;
    const int row0   = (bx >> 1) * TMA;
    const int cb     = colblk * NCB;

    const int arow = tid >> 3;          // 0..63
    const int aq   = tid & 7;
    const int acol = ((aq >> 1) ^ ((arow >> 1) & 3)) * 8 + (aq & 1) * 4;

    // Blo fragment sources (per ct): 16B contiguous per lane
    const unsigned short* blsrc[4];
    #pragma unroll
    for (int ct = 0; ct < 4; ++ct)
        blsrc[ct] = w1lo + (size_t)(cb + cgrp * 64 + ct * 16 + l15) * DIM + lg * 8;

    f32x4 acc[2][4];
    #pragma unroll
    for (int rt = 0; rt < 2; ++rt)
        #pragma unroll
        for (int ct = 0; ct < 4; ++ct) acc[rt][ct] = (f32x4)0.f;

    auto stageB = [&](int t, int buf) {      // 2 gload_lds (hi only)
        unsigned short* bh = smem + buf * 12288;
        #pragma unroll
        for (int r = 0; r < 2; ++r) {
            int f = r * 512 + tid;           // chunk 0..1023
            int n = f >> 2;                  // local col 0..255
            int j = f & 3;
            int js = j ^ ((n >> 1) & 3);
            __builtin_amdgcn_global_load_lds(
                (const __attribute__((address_space(1))) void*)(w1hi + (size_t)(cb + n) * DIM + t * BK + js * 8),
                (__attribute__((address_space(3))) void*)(bh + f * 8), 16, 0, 0);
        }
    };
    auto stageA = [&](int t, int buf) {
        float4 g4 = *reinterpret_cast<const float4*>(
                        &G[(size_t)(row0 + arow) * DIM + t * BK + aq * 4]);
        float xs[4] = {g4.x, g4.y, g4.z, g4.w};
        unsigned short h[4], l[4];
        #pragma unroll
        for (int i = 0; i < 4; ++i) {
            h[i] = bf16_rne(xs[i]);
            float rem = xs[i] - bf16_to_f(h[i]);
            l[i] = bf16_rne(rem);
        }
        ushort4 h4, l4;
        h4.x = h[0]; h4.y = h[1]; h4.z = h[2]; h4.w = h[3];
        l4.x = l[0]; l4.y = l[1]; l4.z = l[2]; l4.w = l[3];
        unsigned short* ab = smem + buf * 12288 + 8192;
        *reinterpret_cast<ushort4*>(&ab[arow * 32 + acol])        = h4;
        *reinterpret_cast<ushort4*>(&ab[2048 + arow * 32 + acol]) = l4;
    };

    stageB(0, 0);
    stageA(0, 0);
    __syncthreads();

    for (int t = 0; t < NT; ++t) {
        const int cur = t & 1;

        // Blo(t) -> regs first (longest latency headroom: consumed in pass 3)
        bf16x8 blr[4];
        #pragma unroll
        for (int ct = 0; ct < 4; ++ct)
            blr[ct] = *reinterpret_cast<const bf16x8*>(blsrc[ct] + t * BK);

        if (t + 1 < NT) {
            stageB(t + 1, cur ^ 1);
            stageA(t + 1, cur ^ 1);
        }
        unsigned short* base = smem + cur * 12288;

        bf16x8 ah[2], al[2], bh[4];
        #pragma unroll
        for (int rt = 0; rt < 2; ++rt) {
            int r_ = rgrp * 32 + rt * 16 + l15;
            int cs = (lg ^ ((r_ >> 1) & 3)) * 8;
            ah[rt] = *reinterpret_cast<const bf16x8*>(&base[8192 + r_ * 32 + cs]);
            al[rt] = *reinterpret_cast<const bf16x8*>(&base[10240 + r_ * 32 + cs]);
        }
        #pragma unroll
        for (int ct = 0; ct < 4; ++ct) {
            int n  = cgrp * 64 + ct * 16 + l15;
            int cs = (lg ^ ((n >> 1) & 3)) * 8;
            bh[ct] = *reinterpret_cast<const bf16x8*>(&base[n * 32 + cs]);
        }
        // per-acc pass order (hh, lh, hl) == rounds 4/6/7/8 (bit-exact)
        #pragma unroll
        for (int ct = 0; ct < 4; ++ct)
            #pragma unroll
            for (int rt = 0; rt < 2; ++rt)
                acc[rt][ct] = __builtin_amdgcn_mfma_f32_16x16x32_bf16(ah[rt], bh[ct], acc[rt][ct], 0, 0, 0);
        #pragma unroll
        for (int ct = 0; ct < 4; ++ct)
            #pragma unroll
            for (int rt = 0; rt < 2; ++rt)
                acc[rt][ct] = __builtin_amdgcn_mfma_f32_16x16x32_bf16(al[rt], bh[ct], acc[rt][ct], 0, 0, 0);
        #pragma unroll
        for (int ct = 0; ct < 4; ++ct)
            #pragma unroll
            for (int rt = 0; rt < 2; ++rt)
                acc[rt][ct] = __builtin_amdgcn_mfma_f32_16x16x32_bf16(ah[rt], blr[ct], acc[rt][ct], 0, 0, 0);
        __syncthreads();
    }

    // ReLU
    #pragma unroll
    for (int rt = 0; rt < 2; ++rt)
        #pragma unroll
        for (int ct = 0; ct < 4; ++ct)
            #pragma unroll
            for (int j = 0; j < 4; ++j)
                acc[rt][ct][j] = fmaxf(acc[rt][ct][j], 0.f);

    // per-wave 64-col logit partial (bit-exact tree, == R7)
    const int w8 = colblk * 4 + cgrp;
    #pragma unroll
    for (int e = 0; e < NEXP; ++e) {
        float w2v[4];
        #pragma unroll
        for (int ct = 0; ct < 4; ++ct)
            w2v[ct] = W2[(size_t)e * DIM + cb + cgrp * 64 + ct * 16 + l15];
        #pragma unroll
        for (int rt = 0; rt < 2; ++rt) {
            #pragma unroll
            for (int j = 0; j < 4; ++j) {
                float s = 0.f;
                #pragma unroll
                for (int ct = 0; ct < 4; ++ct)
                    s = fmaf(acc[rt][ct][j], w2v[ct], s);
                s += __shfl_xor(s, 1, 16);
                s += __shfl_xor(s, 2, 16);
                s += __shfl_xor(s, 4, 16);
                s += __shfl_xor(s, 8, 16);
                if (l15 == 0) {
                    int grow = row0 + rgrp * 32 + rt * 16 + lg * 4 + j;
                    plogG[((size_t)grow * 8 + w8) * NEXP + e] = s;
                }
            }
        }
    }
}

// ---------------- kernel B: reduce 8 partials + softmax/top-5 + output -----
__global__ __launch_bounds__(256)
void finalize(const float* __restrict__ plogG, const float* __restrict__ value,
              const float* __restrict__ shsum, const float* __restrict__ routing_w,
              float* __restrict__ out)
{
    __shared__ float swls[TMF * NEXP];
    const int tid  = threadIdx.x;
    const int row0 = blockIdx.x * TMF;

    if (tid < TMF) {
        const float* pr = &plogG[(size_t)(row0 + tid) * 8 * NEXP];
        float lgt[NEXP];
        #pragma unroll
        for (int e = 0; e < NEXP; ++e) lgt[e] = 0.f;
        #pragma unroll
        for (int w = 0; w < 8; ++w)        // sequential w-order (bit-exact)
            #pragma unroll
            for (int e = 0; e < NEXP; ++e)
                lgt[e] += pr[w * NEXP + e];

        float mx = lgt[0];
        #pragma unroll
        for (int e = 1; e < NEXP; ++e) mx = fmaxf(mx, lgt[e]);
        float p[NEXP], se = 0.f;
        #pragma unroll
        for (int e = 0; e < NEXP; ++e) { p[e] = expf(lgt[e] - mx); se += p[e]; }
        float inv = 1.f / se;
        #pragma unroll
        for (int e = 0; e < NEXP; ++e) p[e] *= inv;
        unsigned used = 0;
        #pragma unroll
        for (int t = 0; t < KTOP; ++t) {
            float bv = -1.f; int bi = 0;
            #pragma unroll
            for (int e = 0; e < NEXP; ++e) {
                bool better = (((used >> e) & 1u) == 0u) && (p[e] > bv);
                bv = better ? p[e] : bv;
                bi = better ? e : bi;
            }
            used |= 1u << bi;
        }
        #pragma unroll
        for (int e = 0; e < NEXP; ++e)
            swls[tid * NEXP + e] = ((used >> e) & 1u) ? p[e] : 0.f;
    }
    __syncthreads();

    const int c4 = (tid & 127) * 4;
    const int rh = tid >> 7;
    float4 sh4 = *reinterpret_cast<const float4*>(&shsum[c4]);
    float4 rw4[NEXP];
    #pragma unroll
    for (int e = 0; e < NEXP; ++e)
        rw4[e] = *reinterpret_cast<const float4*>(&routing_w[(size_t)e * DIM + c4]);
    #pragma unroll
    for (int r = 0; r < 16; ++r) {
        int row = rh * 16 + r;
        float val = value[row0 + row];
        float4 o = sh4;
        #pragma unroll
        for (int e = 0; e < NEXP; ++e) {
            float wgt = swls[row * NEXP + e];
            o.x = fmaf(wgt, rw4[e].x, o.x);
            o.y = fmaf(wgt, rw4[e].y, o.y);
            o.z = fmaf(wgt, rw4[e].z, o.z);
            o.w = fmaf(wgt, rw4[e].w, o.w);
        }
        o.x *= val; o.y *= val; o.z *= val; o.w *= val;
        *reinterpret_cast<float4*>(&out[(size_t)(row0 + row) * DIM + c4]) = o;
    }
}

extern "C" void kernel_launch(void* const* d_in, const int* in_sizes, int n_in,
                              void* d_out, int out_size, void* d_ws, size_t ws_size,
                              hipStream_t stream) {
    const float* G         = (const float*)d_in[0];
    const float* value     = (const float*)d_in[1];
    const float* shared_w  = (const float*)d_in[2];
    const float* routing_w = (const float*)d_in[3];
    const float* W1        = (const float*)d_in[4];
    const float* W2        = (const float*)d_in[5];
    float* out             = (float*)d_out;

    unsigned short* w1hi = (unsigned short*)d_ws;                        // 512 KB
    unsigned short* w1lo = (unsigned short*)((char*)d_ws + 524288);      // 512 KB
    float*          shs  = (float*)((char*)d_ws + 1048576);              // 2 KB
    float*          plg  = (float*)((char*)d_ws + 1056768);              // 5.12 MB

    prep_kernel<<<257, 256, 0, stream>>>(W1, shared_w, w1hi, w1lo, shs);
    gemm_logits<<<(M_ROWS / TMA) * 2, 512, 0, stream>>>(G, w1hi, w1lo, W2, plg);
    finalize<<<M_ROWS / TMF, 256, 0, stream>>>(plg, value, shs, routing_w, out);
}

// Round 15
// 74.540 us; speedup vs baseline: 1.8090x; 1.0311x over previous
//
#include <hip/hip_runtime.h>

constexpr int M_ROWS = 16000;   // B*T
constexpr int DIM    = 512;
constexpr int NEXP   = 10;
constexpr int NSH    = 5;
constexpr int KTOP   = 5;

constexpr int TMA = 64;         // rows per gemm block
constexpr int NCB = 256;        // cols per gemm block (2 col-blocks)
constexpr int BK  = 32;         // k-tile
constexpr int NT  = DIM / BK;   // 16

constexpr int TMF = 32;         // rows per finalize block

typedef __attribute__((ext_vector_type(8))) short  bf16x8;
typedef __attribute__((ext_vector_type(4))) float  f32x4;

__device__ inline unsigned short bf16_rne(float x) {
    unsigned u = __float_as_uint(x);
    u += 0x7fffu + ((u >> 16) & 1u);
    return (unsigned short)(u >> 16);
}
__device__ inline float bf16_to_f(unsigned short h) {
    return __uint_as_float(((unsigned)h) << 16);
}

// ---------------- prep: W1 -> (hi,lo) bf16 [N][K]; shsum = sum_s shared_w ----
__global__ __launch_bounds__(256)
void prep_kernel(const float* __restrict__ W1, const float* __restrict__ shared_w,
                 unsigned short* __restrict__ w1hi, unsigned short* __restrict__ w1lo,
                 float* __restrict__ shsum)
{
    int b = blockIdx.x;
    if (b < 256) {
        int f = b * 256 + threadIdx.x;
        float4 v = *reinterpret_cast<const float4*>(&W1[(size_t)f * 4]);
        float xs[4] = {v.x, v.y, v.z, v.w};
        ushort4 h4, l4;
        unsigned short h[4], l[4];
        #pragma unroll
        for (int i = 0; i < 4; ++i) {
            h[i] = bf16_rne(xs[i]);
            float rem = xs[i] - bf16_to_f(h[i]);
            l[i] = bf16_rne(rem);
        }
        h4.x = h[0]; h4.y = h[1]; h4.z = h[2]; h4.w = h[3];
        l4.x = l[0]; l4.y = l[1]; l4.z = l[2]; l4.w = l[3];
        *reinterpret_cast<ushort4*>(&w1hi[(size_t)f * 4]) = h4;
        *reinterpret_cast<ushort4*>(&w1lo[(size_t)f * 4]) = l4;
    } else {
        for (int c = threadIdx.x; c < DIM; c += 256) {
            float s = 0.f;
            #pragma unroll
            for (int e = 0; e < NSH; ++e) s += shared_w[e * DIM + c];
            shsum[c] = s;
        }
    }
}

// ---------------- prep_g: G fp32 -> (ghi, glo) bf16, row-major [M][D] -------
// ghi/glo live in d_out (32.77 MB scratch, exactly out-bytes); finalize
// fully overwrites d_out afterwards — deterministic across graph replays.
// Values: identical bf16_rne/remainder as R7's in-loop stageA (bit-exact).
__global__ __launch_bounds__(256)
void prep_g(const float* __restrict__ G,
            unsigned short* __restrict__ ghi, unsigned short* __restrict__ glo)
{
    int i = blockIdx.x * 256 + threadIdx.x;       // 0..511999
    #pragma unroll
    for (int r = 0; r < 4; ++r) {
        int f = i + r * 512000;                   // float4 index, 0..2047999
        float4 v = reinterpret_cast<const float4*>(G)[f];
        float xs[4] = {v.x, v.y, v.z, v.w};
        unsigned short h[4], l[4];
        #pragma unroll
        for (int k = 0; k < 4; ++k) {
            h[k] = bf16_rne(xs[k]);
            float rem = xs[k] - bf16_to_f(h[k]);  // exact in fp32
            l[k] = bf16_rne(rem);
        }
        ushort4 h4, l4;
        h4.x = h[0]; h4.y = h[1]; h4.z = h[2]; h4.w = h[3];
        l4.x = l[0]; l4.y = l[1]; l4.z = l[2]; l4.w = l[3];
        reinterpret_cast<ushort4*>(ghi)[f] = h4;
        reinterpret_cast<ushort4*>(glo)[f] = l4;
    }
}

// ---------------- kernel A: 3-pass GEMM + partial logits ----------------
// R7-verbatim structure (verified 7x: 45.7us, absmax 9.77e-4) with the A-path
// stripped from the loop: A now staged via 1 global_load_lds per thread from
// pre-converted ghi/glo (waves 0-3 stage Ahi, waves 4-7 Alo; wave-uniform LDS
// dest + lane x 16B per m104; pre-swizzled SOURCE, both-sides rule). Zero
// in-loop VALU conversion, zero ds_writes, no lgkm drain content at barriers.
// 250x2 blocks, 512 thr = 8 waves, wave (rgrp=wv>>2,cgrp=wv&3) = 32r x 64c,
// acc[2][4]. LDS 80KB (2 bufs x 20480 shorts: Bh@0, Bl@8192, Ah@16384,
// Al@18432) -> 2 blocks/CU. Chunk swizzle phys16B = logical^((row>>1)&3).
// BIT-EXACT (3-pass mandatory; R12: one top-k flip = 2.5e-2 output error):
// same bf16 values (prep_g == old stageA conversion), same fragment maps,
// per-acc pass order (hh,lh,hl), t ascending, same 64-col fmaf chain +
// width-16 butterfly, w8=colblk*4+cgrp, finalize sums w=0..7 sequentially.
__global__ __launch_bounds__(512, 4)
void gemm_logits(const unsigned short* __restrict__ ghi,
                 const unsigned short* __restrict__ glo,
                 const unsigned short* __restrict__ w1hi,
                 const unsigned short* __restrict__ w1lo,
                 const float* __restrict__ W2,
                 float* __restrict__ plogG)
{
    __shared__ unsigned short smem[40960];   // 81920 B

    const int tid  = threadIdx.x;
    const int lane = tid & 63;
    const int wv   = tid >> 6;          // 0..7
    const int l15  = lane & 15;
    const int lg   = lane >> 4;
    const int rgrp = wv >> 2;           // 0..1
    const int cgrp = wv & 3;            // 0..3
    const int bx     = blockIdx.x;
    const int colblk = bx & 1;
    const int row0   = (bx >> 1) * TMA;
    const int cb     = colblk * NCB;

    // ---- A staging: one chunk per thread (hi for tid<256, lo otherwise) ----
    const int af   = tid & 255;         // chunk id 0..255
    const int arow = af >> 2;           // 0..63
    const int ajs  = (af & 3) ^ ((arow >> 1) & 3);
    const unsigned short* asrc =
        (tid < 256 ? ghi : glo) + (size_t)(row0 + arow) * DIM + ajs * 8;
    const int adst = (tid < 256 ? 16384 : 18432) + af * 8;   // shorts

    f32x4 acc[2][4];
    #pragma unroll
    for (int rt = 0; rt < 2; ++rt)
        #pragma unroll
        for (int ct = 0; ct < 4; ++ct) acc[rt][ct] = (f32x4)0.f;

    auto stageB = [&](int t, int buf) {      // 4 gload_lds
        unsigned short* bh = smem + buf * 20480;
        unsigned short* bl = bh + 8192;
        #pragma unroll
        for (int r = 0; r < 2; ++r) {
            int f = r * 512 + tid;           // chunk 0..1023
            int n = f >> 2;                  // local col 0..255
            int js = (f & 3) ^ ((n >> 1) & 3);
            __builtin_amdgcn_global_load_lds(
                (const __attribute__((address_space(1))) void*)(w1hi + (size_t)(cb + n) * DIM + t * BK + js * 8),
                (__attribute__((address_space(3))) void*)(bh + f * 8), 16, 0, 0);
        }
        #pragma unroll
        for (int r = 0; r < 2; ++r) {
            int f = r * 512 + tid;
            int n = f >> 2;
            int js = (f & 3) ^ ((n >> 1) & 3);
            __builtin_amdgcn_global_load_lds(
                (const __attribute__((address_space(1))) void*)(w1lo + (size_t)(cb + n) * DIM + t * BK + js * 8),
                (__attribute__((address_space(3))) void*)(bl + f * 8), 16, 0, 0);
        }
    };
    auto stageA = [&](int t, int buf) {      // 1 gload_lds
        __builtin_amdgcn_global_load_lds(
            (const __attribute__((address_space(1))) void*)(asrc + t * BK),
            (__attribute__((address_space(3))) void*)(smem + buf * 20480 + adst), 16, 0, 0);
    };

    stageB(0, 0);
    stageA(0, 0);
    __syncthreads();

    for (int t = 0; t < NT; ++t) {
        const int cur = t & 1;
        if (t + 1 < NT) {
            stageB(t + 1, cur ^ 1);
            stageA(t + 1, cur ^ 1);
        }
        unsigned short* base = smem + cur * 20480;

        bf16x8 ah[2], al[2], bh[4], bl[4];
        #pragma unroll
        for (int rt = 0; rt < 2; ++rt) {
            int r_ = rgrp * 32 + rt * 16 + l15;
            int cs = (lg ^ ((r_ >> 1) & 3)) * 8;
            ah[rt] = *reinterpret_cast<const bf16x8*>(&base[16384 + r_ * 32 + cs]);
            al[rt] = *reinterpret_cast<const bf16x8*>(&base[18432 + r_ * 32 + cs]);
        }
        #pragma unroll
        for (int ct = 0; ct < 4; ++ct) {
            int n  = cgrp * 64 + ct * 16 + l15;
            int cs = (lg ^ ((n >> 1) & 3)) * 8;
            bh[ct] = *reinterpret_cast<const bf16x8*>(&base[n * 32 + cs]);
            bl[ct] = *reinterpret_cast<const bf16x8*>(&base[8192 + n * 32 + cs]);
        }
        // per-acc pass order (hh, lh, hl) == rounds 4/6/7/8 (bit-exact)
        #pragma unroll
        for (int ct = 0; ct < 4; ++ct)
            #pragma unroll
            for (int rt = 0; rt < 2; ++rt)
                acc[rt][ct] = __builtin_amdgcn_mfma_f32_16x16x32_bf16(ah[rt], bh[ct], acc[rt][ct], 0, 0, 0);
        #pragma unroll
        for (int ct = 0; ct < 4; ++ct)
            #pragma unroll
            for (int rt = 0; rt < 2; ++rt)
                acc[rt][ct] = __builtin_amdgcn_mfma_f32_16x16x32_bf16(al[rt], bh[ct], acc[rt][ct], 0, 0, 0);
        #pragma unroll
        for (int ct = 0; ct < 4; ++ct)
            #pragma unroll
            for (int rt = 0; rt < 2; ++rt)
                acc[rt][ct] = __builtin_amdgcn_mfma_f32_16x16x32_bf16(ah[rt], bl[ct], acc[rt][ct], 0, 0, 0);
        __syncthreads();
    }

    // ReLU
    #pragma unroll
    for (int rt = 0; rt < 2; ++rt)
        #pragma unroll
        for (int ct = 0; ct < 4; ++ct)
            #pragma unroll
            for (int j = 0; j < 4; ++j)
                acc[rt][ct][j] = fmaxf(acc[rt][ct][j], 0.f);

    // per-wave 64-col logit partial (bit-exact tree, == R7)
    const int w8 = colblk * 4 + cgrp;
    #pragma unroll
    for (int e = 0; e < NEXP; ++e) {
        float w2v[4];
        #pragma unroll
        for (int ct = 0; ct < 4; ++ct)
            w2v[ct] = W2[(size_t)e * DIM + cb + cgrp * 64 + ct * 16 + l15];
        #pragma unroll
        for (int rt = 0; rt < 2; ++rt) {
            #pragma unroll
            for (int j = 0; j < 4; ++j) {
                float s = 0.f;
                #pragma unroll
                for (int ct = 0; ct < 4; ++ct)
                    s = fmaf(acc[rt][ct][j], w2v[ct], s);
                s += __shfl_xor(s, 1, 16);
                s += __shfl_xor(s, 2, 16);
                s += __shfl_xor(s, 4, 16);
                s += __shfl_xor(s, 8, 16);
                if (l15 == 0) {
                    int grow = row0 + rgrp * 32 + rt * 16 + lg * 4 + j;
                    plogG[((size_t)grow * 8 + w8) * NEXP + e] = s;
                }
            }
        }
    }
}

// ---------------- kernel B: reduce 8 partials + softmax/top-5 + output -----
__global__ __launch_bounds__(256)
void finalize(const float* __restrict__ plogG, const float* __restrict__ value,
              const float* __restrict__ shsum, const float* __restrict__ routing_w,
              float* __restrict__ out)
{
    __shared__ float swls[TMF * NEXP];
    const int tid  = threadIdx.x;
    const int row0 = blockIdx.x * TMF;

    if (tid < TMF) {
        const float* pr = &plogG[(size_t)(row0 + tid) * 8 * NEXP];
        float lgt[NEXP];
        #pragma unroll
        for (int e = 0; e < NEXP; ++e) lgt[e] = 0.f;
        #pragma unroll
        for (int w = 0; w < 8; ++w)        // sequential w-order (bit-exact)
            #pragma unroll
            for (int e = 0; e < NEXP; ++e)
                lgt[e] += pr[w * NEXP + e];

        float mx = lgt[0];
        #pragma unroll
        for (int e = 1; e < NEXP; ++e) mx = fmaxf(mx, lgt[e]);
        float p[NEXP], se = 0.f;
        #pragma unroll
        for (int e = 0; e < NEXP; ++e) { p[e] = expf(lgt[e] - mx); se += p[e]; }
        float inv = 1.f / se;
        #pragma unroll
        for (int e = 0; e < NEXP; ++e) p[e] *= inv;
        unsigned used = 0;
        #pragma unroll
        for (int t = 0; t < KTOP; ++t) {
            float bv = -1.f; int bi = 0;
            #pragma unroll
            for (int e = 0; e < NEXP; ++e) {
                bool better = (((used >> e) & 1u) == 0u) && (p[e] > bv);
                bv = better ? p[e] : bv;
                bi = better ? e : bi;
            }
            used |= 1u << bi;
        }
        #pragma unroll
        for (int e = 0; e < NEXP; ++e)
            swls[tid * NEXP + e] = ((used >> e) & 1u) ? p[e] : 0.f;
    }
    __syncthreads();

    const int c4 = (tid & 127) * 4;
    const int rh = tid >> 7;
    float4 sh4 = *reinterpret_cast<const float4*>(&shsum[c4]);
    float4 rw4[NEXP];
    #pragma unroll
    for (int e = 0; e < NEXP; ++e)
        rw4[e] = *reinterpret_cast<const float4*>(&routing_w[(size_t)e * DIM + c4]);
    #pragma unroll
    for (int r = 0; r < 16; ++r) {
        int row = rh * 16 + r;
        float val = value[row0 + row];
        float4 o = sh4;
        #pragma unroll
        for (int e = 0; e < NEXP; ++e) {
            float wgt = swls[row * NEXP + e];
            o.x = fmaf(wgt, rw4[e].x, o.x);
            o.y = fmaf(wgt, rw4[e].y, o.y);
            o.z = fmaf(wgt, rw4[e].z, o.z);
            o.w = fmaf(wgt, rw4[e].w, o.w);
        }
        o.x *= val; o.y *= val; o.z *= val; o.w *= val;
        *reinterpret_cast<float4*>(&out[(size_t)(row0 + row) * DIM + c4]) = o;
    }
}

extern "C" void kernel_launch(void* const* d_in, const int* in_sizes, int n_in,
                              void* d_out, int out_size, void* d_ws, size_t ws_size,
                              hipStream_t stream) {
    const float* G         = (const float*)d_in[0];
    const float* value     = (const float*)d_in[1];
    const float* shared_w  = (const float*)d_in[2];
    const float* routing_w = (const float*)d_in[3];
    const float* W1        = (const float*)d_in[4];
    const float* W2        = (const float*)d_in[5];
    float* out             = (float*)d_out;

    unsigned short* w1hi = (unsigned short*)d_ws;                        // 512 KB
    unsigned short* w1lo = (unsigned short*)((char*)d_ws + 524288);      // 512 KB
    float*          shs  = (float*)((char*)d_ws + 1048576);              // 2 KB
    float*          plg  = (float*)((char*)d_ws + 1056768);              // 5.12 MB

    // ghi/glo scratch inside d_out (exactly out-bytes = 32.77 MB);
    // finalize fully overwrites d_out afterwards.
    unsigned short* ghi = (unsigned short*)d_out;                        // 16.38 MB
    unsigned short* glo = ghi + (size_t)M_ROWS * DIM;                    // 16.38 MB

    prep_kernel<<<257, 256, 0, stream>>>(W1, shared_w, w1hi, w1lo, shs);
    prep_g<<<2000, 256, 0, stream>>>(G, ghi, glo);
    gemm_logits<<<(M_ROWS / TMA) * 2, 512, 0, stream>>>(ghi, glo, w1hi, w1lo, W2, plg);
    finalize<<<M_ROWS / TMF, 256, 0, stream>>>(plg, value, shs, routing_w, out);
}